// Round 19
// baseline (51357.143 us; speedup 1.0000x reference)
//
#include <hip/hip_runtime.h>
#include <math.h>

// DummyRNN: h = tanh(x_t*w_ih + b_ih + W_hh@h + b_hh); y_t = W_out@h + b_out
//
// R19 = R18 (4-way chain interleave, 64 chains x 320 steps, XCD-local
// flag-split sync, W_hh bf16 in LDS, group demote escape hatch) with the
// rotation body BATCHED into 4 phases so the 4 chains' L2 round trips
// overlap instead of serializing:
//   compute(all 4, W read once per element) -> publish(4 stores, ONE vmcnt,
//   4 flags) -> poll(ONE asm: 4 flag loads + vmcnt per sweep) -> load(ONE
//   asm: 16 dwordx4 + vmcnt). Dependent round trips/rotation: ~10 -> 3.

#define H      1024
#define TSTEPS 20480
#define BLOCK  256
#define WARM   64
#define WGSPC  16

typedef unsigned int uint;
typedef float f32x4 __attribute__((ext_vector_type(4)));

#define HDATA_BYTES ((size_t)64 * 2 * H * sizeof(float))   // 512 KB (coop)

__device__ __forceinline__ uint f2bf(float f) {            // fp32 -> bf16 RNE
    uint u = __float_as_uint(f);
    return (u + 0x7fffu + ((u >> 16) & 1u)) >> 16;
}

__global__ __launch_bounds__(BLOCK, 1)
void rnn_r19(const float* __restrict__ xs, const float* __restrict__ W_ih,
             const float* __restrict__ b_ih, const float* __restrict__ W_hh,
             const float* __restrict__ b_hh, const float* __restrict__ W_out,
             const float* __restrict__ b_out, float* __restrict__ y,
             float* __restrict__ hdata, uint* __restrict__ ctrl,
             int coop, int ilv, int chunk)
{
    const int tid  = threadIdx.x;
    const int bid  = blockIdx.x;
    const int wave = tid >> 6;
    const int lane = tid & 63;

    __shared__ uint  sW[64][512];    // 128 KB: 64 rows of W_hh as bf16 pairs
    __shared__ uint  sR[256];
    __shared__ int   sA[3];
    __shared__ float sY[4][4][8];    // [wave][k][it>>6] parked y (coop)

    uint* rcount = ctrl;             // [0]
    uint* abortf = ctrl + 16;        // [16..31] per-GROUP abort flags
    uint* roster = ctrl + 64;        // [64..319]
    uint* flbase = ctrl + 1024;      // 64 chains x 64 per-wave flags

    int group, slot; bool fastm;
    if (coop) {
        uint xcc = __builtin_amdgcn_s_getreg(20 | (31 << 11)) & 7u; // HW_REG_XCC_ID
        if (tid == 0) {
            __hip_atomic_store(&roster[bid], xcc, __ATOMIC_RELAXED, __HIP_MEMORY_SCOPE_AGENT);
            asm volatile("s_waitcnt vmcnt(0)" ::: "memory");
            atomicAdd(rcount, 1u);
            while (__hip_atomic_load(rcount, __ATOMIC_RELAXED, __HIP_MEMORY_SCOPE_AGENT) < 256u)
                __builtin_amdgcn_s_sleep(2);
        }
        __syncthreads();
        sR[tid] = __hip_atomic_load(&roster[tid], __ATOMIC_RELAXED, __HIP_MEMORY_SCOPE_AGENT);
        __syncthreads();
        if (tid == 0) {
            int cnt[8] = {0,0,0,0,0,0,0,0};
            int myrank = 0, myx = 0;
            for (int b = 0; b < 256; ++b) {
                int x = (int)(sR[b] & 7u);
                int r = cnt[x]++;
                if (b == bid) { myrank = r; myx = x; }
            }
            int pre[9]; pre[0] = 0;
            for (int x = 0; x < 8; ++x) pre[x + 1] = pre[x] + cnt[x];
            int gidx = pre[myx] + myrank;
            int gr = gidx >> 4, sl = gidx & 15;
            int lo = gr << 4, hi = lo + 16, fok = 0;
            for (int x = 0; x < 8; ++x)
                if (pre[x] <= lo && hi <= pre[x + 1]) fok = 1;
            sA[0] = gr; sA[1] = sl; sA[2] = fok;
        }
        __syncthreads();
        group = sA[0]; slot = sA[1]; fastm = (sA[2] != 0);
    } else {
        group = bid / WGSPC; slot = bid % WGSPC; fastm = false;
    }

    uint* abortp = abortf + group;
    const int wic     = slot * 4 + wave;
    const int rowbase = slot * 64 + wave * 16;
    const int rowwg   = slot * 64;
    const int ck0     = group * ilv;

    // ---- one-time: stage the WG's 64 W_hh rows into LDS as bf16 pairs ----
    for (int idx = tid; idx < 64 * 512; idx += BLOCK) {
        const int r = idx >> 9, p = idx & 511;
        const float2 w = *(const float2*)&W_hh[(size_t)(rowwg + r) * H + 2 * p];
        sW[r][p] = f2bf(w.x) | (f2bf(w.y) << 16);
    }
    __syncthreads();

    const int myrow = rowbase + (lane & 15);
    const float wih_s = W_ih[myrow];
    const float cb_s  = b_ih[myrow] + b_hh[myrow];

    f32x4 wo4[4];
    #pragma unroll
    for (int q = 0; q < 4; ++q)
        wo4[q] = *(const f32x4*)&W_out[256 * q + 4 * lane];
    const float bo = b_out[0];

    // per-chain geometry
    int ns[4], t0c[4];
    #pragma unroll
    for (int k = 0; k < 4; ++k) {
        const int ck = ck0 + k;
        const int w_ = (k < ilv && ck) ? WARM : 0;
        ns[k]  = (k < ilv) ? chunk + w_ : 0;
        t0c[k] = ck * chunk - w_;
    }

    f32x4 hrv[4][4] = {};            // hrv[k][q] = h[256q + 4l .. +3], h_0=0
    float lv0[4] = {0,0,0,0}, lv1[4] = {0,0,0,0};
    uint  lastflag[4] = {0,0,0,0};
    float xcur[4] = {0,0,0,0};
    #pragma unroll
    for (int k = 0; k < 4; ++k)
        if (k < ilv) xcur[k] = xs[t0c[k]];

    auto demote = [&]() {
        #pragma unroll
        for (int k = 0; k < 4; ++k) {
            if (k >= ilv) continue;
            float* hbk = hdata + (size_t)(ck0 + k) * 2 * H;
            float* q0 = hbk + rowbase + (lane & 15);
            float* q1 = q0 + H;
            if (lane < 16) {
                asm volatile("global_store_dword %0, %1, off sc0 sc1"
                             :: "v"(q0), "v"(lv0[k]) : "memory");
                asm volatile("global_store_dword %0, %1, off sc0 sc1"
                             :: "v"(q1), "v"(lv1[k]) : "memory");
            }
            asm volatile("s_waitcnt vmcnt(0)" ::: "memory");
            if (lane == 0)
                asm volatile("global_store_dword %0, %1, off sc0 sc1"
                             :: "v"(flbase + (ck0 + k) * 64 + wic), "v"(lastflag[k]) : "memory");
        }
        asm volatile("s_waitcnt vmcnt(0)" ::: "memory");
        if (lane == 0)
            asm volatile("global_store_dword %0, %1, off sc0 sc1"
                         :: "v"(abortp), "v"(1u) : "memory");
        asm volatile("s_waitcnt vmcnt(0)" ::: "memory");
        fastm = false;
    };

    auto abort_set = [&]() -> bool {
        uint ab;
        asm volatile("global_load_dword %0, %1, off sc0 sc1\n\ts_waitcnt vmcnt(0)"
                     : "=v"(ab) : "v"(abortp) : "memory");
        return __any(ab != 0u);
    };

    // single-chain poll+load (fallback path + tails); writes out[16]
    auto poll_load_t = [&](int ck, int lt, float* out) {
        const uint* fa = flbase + ck * 64 + lane;
        const uint tt = (uint)lt;
        uint fails = 0;
        for (;;) {
            uint f;
            if (fastm)
                asm volatile("global_load_dword %0, %1, off sc0\n\ts_waitcnt vmcnt(0)"
                             : "=v"(f) : "v"(fa) : "memory");
            else
                asm volatile("global_load_dword %0, %1, off sc0 sc1\n\ts_waitcnt vmcnt(0)"
                             : "=v"(f) : "v"(fa) : "memory");
            if (__all(f >= tt)) break;
            ++fails;
            if (fastm) {
                if ((fails & 63u) == 0u) {
                    if (abort_set() || fails > 8192u) demote();
                }
                __builtin_amdgcn_s_sleep(1);
            } else {
                __builtin_amdgcn_s_sleep(8);
            }
        }
        const float* a = hdata + (size_t)ck * 2 * H + (size_t)(lt & 1) * H + 4 * lane;
        f32x4 A, B, C, D;
        if (fastm)
            asm volatile(
                "global_load_dwordx4 %0, %4, off sc0\n\t"
                "global_load_dwordx4 %1, %4, off offset:1024 sc0\n\t"
                "global_load_dwordx4 %2, %4, off offset:2048 sc0\n\t"
                "global_load_dwordx4 %3, %4, off offset:3072 sc0\n\t"
                "s_waitcnt vmcnt(0)"
                : "=&v"(A), "=&v"(B), "=&v"(C), "=&v"(D) : "v"(a) : "memory");
        else
            asm volatile(
                "global_load_dwordx4 %0, %4, off sc0 sc1\n\t"
                "global_load_dwordx4 %1, %4, off offset:1024 sc0 sc1\n\t"
                "global_load_dwordx4 %2, %4, off offset:2048 sc0 sc1\n\t"
                "global_load_dwordx4 %3, %4, off offset:3072 sc0 sc1\n\t"
                "s_waitcnt vmcnt(0)"
                : "=&v"(A), "=&v"(B), "=&v"(C), "=&v"(D) : "v"(a) : "memory");
        #pragma unroll
        for (int e = 0; e < 4; ++e) {
            out[e] = A[e]; out[4 + e] = B[e]; out[8 + e] = C[e]; out[12 + e] = D[e];
        }
    };

    // 16-lane tree transpose-reduce (z[16] -> full sum of row rowbase+(l&15))
    auto reduce16 = [&](const float* z) -> float {
        float s0,s1,s2,s3,s4,s5,s6,s7;
        {
            const bool b = (lane & 1) != 0;
            s0 = (b ? z[ 1] : z[ 0]) + __shfl_xor(b ? z[ 0] : z[ 1], 1);
            s1 = (b ? z[ 3] : z[ 2]) + __shfl_xor(b ? z[ 2] : z[ 3], 1);
            s2 = (b ? z[ 5] : z[ 4]) + __shfl_xor(b ? z[ 4] : z[ 5], 1);
            s3 = (b ? z[ 7] : z[ 6]) + __shfl_xor(b ? z[ 6] : z[ 7], 1);
            s4 = (b ? z[ 9] : z[ 8]) + __shfl_xor(b ? z[ 8] : z[ 9], 1);
            s5 = (b ? z[11] : z[10]) + __shfl_xor(b ? z[10] : z[11], 1);
            s6 = (b ? z[13] : z[12]) + __shfl_xor(b ? z[12] : z[13], 1);
            s7 = (b ? z[15] : z[14]) + __shfl_xor(b ? z[14] : z[15], 1);
        }
        float t0_,t1_,t2_,t3_;
        {
            const bool b = (lane & 2) != 0;
            t0_ = (b ? s1 : s0) + __shfl_xor(b ? s0 : s1, 2);
            t1_ = (b ? s3 : s2) + __shfl_xor(b ? s2 : s3, 2);
            t2_ = (b ? s5 : s4) + __shfl_xor(b ? s4 : s5, 2);
            t3_ = (b ? s7 : s6) + __shfl_xor(b ? s6 : s7, 2);
        }
        float u0_,u1_;
        {
            const bool b = (lane & 4) != 0;
            u0_ = (b ? t1_ : t0_) + __shfl_xor(b ? t0_ : t1_, 4);
            u1_ = (b ? t3_ : t2_) + __shfl_xor(b ? t2_ : t3_, 4);
        }
        float zr;
        {
            const bool b = (lane & 8) != 0;
            zr = (b ? u1_ : u0_) + __shfl_xor(b ? u0_ : u1_, 8);
        }
        zr += __shfl_xor(zr, 16);
        zr += __shfl_xor(zr, 32);
        return zr;
    };

    const int nstep_max = chunk + ((ilv > 1 || group) ? WARM : 0);

    #pragma unroll 1
    for (int it = 0; it < nstep_max; ++it) {
        if (fastm && (it & 31) == 1) {
            if (abort_set()) demote();
        }

        // ---- phase 1: compute all chains (W element read ONCE, 4 FMAs) ----
        float z0[16], z1[16], z2[16], z3[16];
        #pragma unroll
        for (int r = 0; r < 16; ++r) {
            const uint2* wrow = (const uint2*)&sW[wave * 16 + r][2 * lane];
            float a0 = 0, a1 = 0, a2 = 0, a3 = 0;
            #pragma unroll
            for (int q = 0; q < 4; ++q) {
                const uint2 u = wrow[q * 64];
                const float w0 = __uint_as_float(u.x << 16);
                const float w1 = __uint_as_float(u.x & 0xffff0000u);
                const float w2 = __uint_as_float(u.y << 16);
                const float w3 = __uint_as_float(u.y & 0xffff0000u);
                a0 = fmaf(w0, hrv[0][q][0], a0); a0 = fmaf(w1, hrv[0][q][1], a0);
                a0 = fmaf(w2, hrv[0][q][2], a0); a0 = fmaf(w3, hrv[0][q][3], a0);
                if (ilv > 1) {
                    a1 = fmaf(w0, hrv[1][q][0], a1); a1 = fmaf(w1, hrv[1][q][1], a1);
                    a1 = fmaf(w2, hrv[1][q][2], a1); a1 = fmaf(w3, hrv[1][q][3], a1);
                    a2 = fmaf(w0, hrv[2][q][0], a2); a2 = fmaf(w1, hrv[2][q][1], a2);
                    a2 = fmaf(w2, hrv[2][q][2], a2); a2 = fmaf(w3, hrv[2][q][3], a2);
                    a3 = fmaf(w0, hrv[3][q][0], a3); a3 = fmaf(w1, hrv[3][q][1], a3);
                    a3 = fmaf(w2, hrv[3][q][2], a3); a3 = fmaf(w3, hrv[3][q][3], a3);
                }
            }
            z0[r] = a0; z1[r] = a1; z2[r] = a2; z3[r] = a3;
        }
        float hv[4];
        hv[0] = tanhf(fmaf(xcur[0], wih_s, cb_s + reduce16(z0)));
        if (ilv > 1) {
            hv[1] = tanhf(fmaf(xcur[1], wih_s, cb_s + reduce16(z1)));
            hv[2] = tanhf(fmaf(xcur[2], wih_s, cb_s + reduce16(z2)));
            hv[3] = tanhf(fmaf(xcur[3], wih_s, cb_s + reduce16(z3)));
        }

        // ---- phase 2: publish all (h stores -> ONE vmcnt -> flag stores) --
        const int par = (it + 1) & 1;
        #pragma unroll
        for (int k = 0; k < 4; ++k) {
            if (k >= ilv || it >= ns[k]) continue;
            float* dst = hdata + (size_t)((ck0 + k) * 2 + par) * H + rowbase + (lane & 15);
            if (lane < 16) {
                if (fastm)
                    asm volatile("global_store_dword %0, %1, off"
                                 :: "v"(dst), "v"(hv[k]) : "memory");
                else
                    asm volatile("global_store_dword %0, %1, off sc0 sc1"
                                 :: "v"(dst), "v"(hv[k]) : "memory");
            }
        }
        asm volatile("s_waitcnt vmcnt(0)" ::: "memory");
        #pragma unroll
        for (int k = 0; k < 4; ++k) {
            if (k >= ilv || it >= ns[k]) continue;
            const uint nf = (uint)(it + 1);
            if (lane == 0) {
                if (fastm)
                    asm volatile("global_store_dword %0, %1, off"
                                 :: "v"(flbase + (ck0 + k) * 64 + wic), "v"(nf) : "memory");
                else
                    asm volatile("global_store_dword %0, %1, off sc0 sc1"
                                 :: "v"(flbase + (ck0 + k) * 64 + wic), "v"(nf) : "memory");
            }
            if (par == 0) lv0[k] = hv[k]; else lv1[k] = hv[k];
            lastflag[k] = nf;
        }

        // ---- y duty (uses h_it = hrv, park in LDS) ----
        #pragma unroll
        for (int k = 0; k < 4; ++k) {
            if (k >= ilv || it >= ns[k]) continue;
            const int warm_k = (ck0 + k) ? WARM : 0;
            if (wic == (it & 63) && it >= warm_k + 1) {
                float acc = 0.0f;
                #pragma unroll
                for (int q = 0; q < 4; ++q) {
                    acc = fmaf(wo4[q][0], hrv[k][q][0], acc);
                    acc = fmaf(wo4[q][1], hrv[k][q][1], acc);
                    acc = fmaf(wo4[q][2], hrv[k][q][2], acc);
                    acc = fmaf(wo4[q][3], hrv[k][q][3], acc);
                }
                #pragma unroll
                for (int off = 32; off > 0; off >>= 1)
                    acc += __shfl_xor(acc, off);
                if (lane == 0) {
                    if (coop) sY[wave][k][it >> 6] = acc + bo;
                    else      y[t0c[k] + it - 1] = acc + bo;
                }
            }
            if (it + 1 < ns[k]) xcur[k] = xs[t0c[k] + it + 1];
        }

        // ---- phases 3+4: combined poll + combined load for step it+1 ----
        if (ilv == 4) {
            uint tg0 = (it + 1 < ns[0]) ? (uint)(it + 1) : 0u;
            uint tg1 = (it + 1 < ns[1]) ? (uint)(it + 1) : 0u;
            uint tg2 = (it + 1 < ns[2]) ? (uint)(it + 1) : 0u;
            uint tg3 = (it + 1 < ns[3]) ? (uint)(it + 1) : 0u;
            if (tg0 | tg1 | tg2 | tg3) {
                const uint* fa = flbase + ck0 * 64 + lane;
                uint fails = 0;
                for (;;) {
                    uint f0, f1, f2, f3;
                    if (fastm)
                        asm volatile(
                            "global_load_dword %0, %4, off sc0\n\t"
                            "global_load_dword %1, %4, off offset:256 sc0\n\t"
                            "global_load_dword %2, %4, off offset:512 sc0\n\t"
                            "global_load_dword %3, %4, off offset:768 sc0\n\t"
                            "s_waitcnt vmcnt(0)"
                            : "=&v"(f0), "=&v"(f1), "=&v"(f2), "=&v"(f3)
                            : "v"(fa) : "memory");
                    else
                        asm volatile(
                            "global_load_dword %0, %4, off sc0 sc1\n\t"
                            "global_load_dword %1, %4, off offset:256 sc0 sc1\n\t"
                            "global_load_dword %2, %4, off offset:512 sc0 sc1\n\t"
                            "global_load_dword %3, %4, off offset:768 sc0 sc1\n\t"
                            "s_waitcnt vmcnt(0)"
                            : "=&v"(f0), "=&v"(f1), "=&v"(f2), "=&v"(f3)
                            : "v"(fa) : "memory");
                    bool ok = (f0 >= tg0) & (f1 >= tg1) & (f2 >= tg2) & (f3 >= tg3);
                    if (__all(ok)) break;
                    ++fails;
                    if (fastm) {
                        if ((fails & 63u) == 0u) {
                            if (abort_set() || fails > 8192u) demote();
                        }
                        __builtin_amdgcn_s_sleep(1);
                    } else {
                        __builtin_amdgcn_s_sleep(8);
                    }
                }
                // combined load: 16 dwordx4, ONE vmcnt
                const float* a0p = hdata + (size_t)(ck0 * 2 + par) * H + 4 * lane;
                const float* a1p = a0p + 2 * H;
                const float* a2p = a0p + 4 * H;
                const float* a3p = a0p + 6 * H;
                if (fastm)
                    asm volatile(
                        "global_load_dwordx4 %0, %16, off sc0\n\t"
                        "global_load_dwordx4 %1, %16, off offset:1024 sc0\n\t"
                        "global_load_dwordx4 %2, %16, off offset:2048 sc0\n\t"
                        "global_load_dwordx4 %3, %16, off offset:3072 sc0\n\t"
                        "global_load_dwordx4 %4, %17, off sc0\n\t"
                        "global_load_dwordx4 %5, %17, off offset:1024 sc0\n\t"
                        "global_load_dwordx4 %6, %17, off offset:2048 sc0\n\t"
                        "global_load_dwordx4 %7, %17, off offset:3072 sc0\n\t"
                        "global_load_dwordx4 %8, %18, off sc0\n\t"
                        "global_load_dwordx4 %9, %18, off offset:1024 sc0\n\t"
                        "global_load_dwordx4 %10, %18, off offset:2048 sc0\n\t"
                        "global_load_dwordx4 %11, %18, off offset:3072 sc0\n\t"
                        "global_load_dwordx4 %12, %19, off sc0\n\t"
                        "global_load_dwordx4 %13, %19, off offset:1024 sc0\n\t"
                        "global_load_dwordx4 %14, %19, off offset:2048 sc0\n\t"
                        "global_load_dwordx4 %15, %19, off offset:3072 sc0\n\t"
                        "s_waitcnt vmcnt(0)"
                        : "=&v"(hrv[0][0]), "=&v"(hrv[0][1]), "=&v"(hrv[0][2]), "=&v"(hrv[0][3]),
                          "=&v"(hrv[1][0]), "=&v"(hrv[1][1]), "=&v"(hrv[1][2]), "=&v"(hrv[1][3]),
                          "=&v"(hrv[2][0]), "=&v"(hrv[2][1]), "=&v"(hrv[2][2]), "=&v"(hrv[2][3]),
                          "=&v"(hrv[3][0]), "=&v"(hrv[3][1]), "=&v"(hrv[3][2]), "=&v"(hrv[3][3])
                        : "v"(a0p), "v"(a1p), "v"(a2p), "v"(a3p) : "memory");
                else
                    asm volatile(
                        "global_load_dwordx4 %0, %16, off sc0 sc1\n\t"
                        "global_load_dwordx4 %1, %16, off offset:1024 sc0 sc1\n\t"
                        "global_load_dwordx4 %2, %16, off offset:2048 sc0 sc1\n\t"
                        "global_load_dwordx4 %3, %16, off offset:3072 sc0 sc1\n\t"
                        "global_load_dwordx4 %4, %17, off sc0 sc1\n\t"
                        "global_load_dwordx4 %5, %17, off offset:1024 sc0 sc1\n\t"
                        "global_load_dwordx4 %6, %17, off offset:2048 sc0 sc1\n\t"
                        "global_load_dwordx4 %7, %17, off offset:3072 sc0 sc1\n\t"
                        "global_load_dwordx4 %8, %18, off sc0 sc1\n\t"
                        "global_load_dwordx4 %9, %18, off offset:1024 sc0 sc1\n\t"
                        "global_load_dwordx4 %10, %18, off offset:2048 sc0 sc1\n\t"
                        "global_load_dwordx4 %11, %18, off offset:3072 sc0 sc1\n\t"
                        "global_load_dwordx4 %12, %19, off sc0 sc1\n\t"
                        "global_load_dwordx4 %13, %19, off offset:1024 sc0 sc1\n\t"
                        "global_load_dwordx4 %14, %19, off offset:2048 sc0 sc1\n\t"
                        "global_load_dwordx4 %15, %19, off offset:3072 sc0 sc1\n\t"
                        "s_waitcnt vmcnt(0)"
                        : "=&v"(hrv[0][0]), "=&v"(hrv[0][1]), "=&v"(hrv[0][2]), "=&v"(hrv[0][3]),
                          "=&v"(hrv[1][0]), "=&v"(hrv[1][1]), "=&v"(hrv[1][2]), "=&v"(hrv[1][3]),
                          "=&v"(hrv[2][0]), "=&v"(hrv[2][1]), "=&v"(hrv[2][2]), "=&v"(hrv[2][3]),
                          "=&v"(hrv[3][0]), "=&v"(hrv[3][1]), "=&v"(hrv[3][2]), "=&v"(hrv[3][3])
                        : "v"(a0p), "v"(a1p), "v"(a2p), "v"(a3p) : "memory");
            }
        } else {
            // fallback (ilv==1): sequential single-chain poll+load
            if (it + 1 < ns[0]) {
                float out[16];
                poll_load_t(ck0, it + 1, out);
                #pragma unroll
                for (int q = 0; q < 4; ++q)
                    #pragma unroll
                    for (int e = 0; e < 4; ++e)
                        hrv[0][q][e] = out[4 * q + e];
            }
        }
    }

    // ---- flush parked y (coop): it = 64*kk + wic -> y[t0+it-1] ----
    if (coop) {
        #pragma unroll
        for (int k = 0; k < 4; ++k) {
            if (k >= ilv) continue;
            const int warm_k = (ck0 + k) ? WARM : 0;
            #pragma unroll 1
            for (int kk = 0; kk < 8; ++kk) {
                const int it = (kk << 6) + wic;
                if (it >= warm_k + 1 && it < ns[k] && lane == 0)
                    y[t0c[k] + it - 1] = sY[wave][k][kk];
            }
        }
    }

    // tail: y[t0+nstep-1] from h_nstep (slot 0, wave 0 per chain)
    if (slot == 0 && wave == 0) {
        #pragma unroll
        for (int k = 0; k < 4; ++k) {
            if (k >= ilv) continue;
            float out[16];
            poll_load_t(ck0 + k, ns[k], out);
            float acc = 0.0f;
            #pragma unroll
            for (int q = 0; q < 4; ++q) {
                acc = fmaf(wo4[q][0], out[4 * q + 0], acc);
                acc = fmaf(wo4[q][1], out[4 * q + 1], acc);
                acc = fmaf(wo4[q][2], out[4 * q + 2], acc);
                acc = fmaf(wo4[q][3], out[4 * q + 3], acc);
            }
            #pragma unroll
            for (int off = 32; off > 0; off >>= 1)
                acc += __shfl_xor(acc, off);
            if (lane == 0) y[t0c[k] + ns[k] - 1] = acc + bo;
        }
    }
}

extern "C" void kernel_launch(void* const* d_in, const int* in_sizes, int n_in,
                              void* d_out, int out_size, void* d_ws, size_t ws_size,
                              hipStream_t stream) {
    const float* xs    = (const float*)d_in[0];
    const float* W_ih  = (const float*)d_in[1];
    const float* b_ih  = (const float*)d_in[2];
    const float* W_hh  = (const float*)d_in[3];
    const float* b_hh  = (const float*)d_in[4];
    const float* W_out = (const float*)d_in[5];
    const float* b_out = (const float*)d_in[6];
    float* y = (float*)d_out;

    const size_t ctrl_bytes = 24576;
    const size_t need = HDATA_BYTES + ctrl_bytes;
    int use_coop = (ws_size >= need) ? 1 : 0;

    float* hdata = (float*)d_ws;
    uint*  ctrl  = (uint*)((char*)d_ws +
                           (use_coop ? HDATA_BYTES
                                     : (size_t)4 * 2 * H * sizeof(float)));

    (void)hipMemsetAsync(d_ws, 0,
                         use_coop ? need
                                  : (size_t)4 * 2 * H * sizeof(float) + ctrl_bytes,
                         stream);

    if (use_coop) {
        int coop = 1, ilv = 4, chunk = TSTEPS / 64;          // 64 chains x 320
        void* args[] = { (void*)&xs, (void*)&W_ih, (void*)&b_ih, (void*)&W_hh,
                         (void*)&b_hh, (void*)&W_out, (void*)&b_out, (void*)&y,
                         (void*)&hdata, (void*)&ctrl,
                         (void*)&coop, (void*)&ilv, (void*)&chunk };
        hipError_t e = hipLaunchCooperativeKernel((const void*)rnn_r19,
                                                  dim3(256), dim3(BLOCK),
                                                  args, 0, stream);
        if (e != hipSuccess) use_coop = 0;
    }
    if (!use_coop) {
        rnn_r19<<<4 * WGSPC, BLOCK, 0, stream>>>(
            xs, W_ih, b_ih, W_hh, b_hh, W_out, b_out, y,
            hdata, ctrl, 0, 1, TSTEPS / 4);
    }
}

// Round 20
// 5985.434 us; speedup vs baseline: 8.5804x; 8.5804x over previous
//
#include <hip/hip_runtime.h>
#include <math.h>

// DummyRNN: h = tanh(x_t*w_ih + b_ih + W_hh@h + b_hh); y_t = W_out@h + b_out
//
// R21 = R19's 3-round-trip rotation WITHOUT the register bomb.
// R19 post-mortem: fused 4-chain compute kept z0..z3 + hrv + temps live ->
// VGPR hit the 256 addressable cap -> scratch spills (WRITE_SIZE 147->315MB)
// -> slow + throttled. R21 computes the 4 chains SEQUENTIALLY (z[16] scoped
// per chain; peak live ~190 VGPR) and keeps the latency win: batched publish
// (one vmcnt for 4 chains) -> combined 4-flag poll (1 RT) -> combined
// 16x dwordx4 h-load (1 RT). Protocol/roster/demote = R18 (proven).

#define H      1024
#define TSTEPS 20480
#define BLOCK  256
#define WARM   64
#define WGSPC  16

typedef unsigned int uint;
typedef float f32x4 __attribute__((ext_vector_type(4)));

#define HDATA_BYTES ((size_t)64 * 2 * H * sizeof(float))   // 512 KB (coop)

__device__ __forceinline__ uint f2bf(float f) {            // fp32 -> bf16 RNE
    uint u = __float_as_uint(f);
    return (u + 0x7fffu + ((u >> 16) & 1u)) >> 16;
}

__global__ __launch_bounds__(BLOCK, 1)
void rnn_r21(const float* __restrict__ xs, const float* __restrict__ W_ih,
             const float* __restrict__ b_ih, const float* __restrict__ W_hh,
             const float* __restrict__ b_hh, const float* __restrict__ W_out,
             const float* __restrict__ b_out, float* __restrict__ y,
             float* __restrict__ hdata, uint* __restrict__ ctrl,
             int coop, int ilv, int chunk)
{
    const int tid  = threadIdx.x;
    const int bid  = blockIdx.x;
    const int wave = tid >> 6;
    const int lane = tid & 63;

    __shared__ uint  sW[64][512];    // 128 KB: 64 rows of W_hh as bf16 pairs
    __shared__ uint  sR[256];
    __shared__ int   sA[3];
    __shared__ float sY[4][4][8];    // [wave][k][it>>6] parked y (coop)

    uint* rcount = ctrl;             // [0]
    uint* abortf = ctrl + 16;        // [16..31] per-GROUP abort flags
    uint* roster = ctrl + 64;        // [64..319]
    uint* flbase = ctrl + 1024;      // 64 chains x 64 per-wave flags

    int group, slot; bool fastm;
    if (coop) {
        uint xcc = __builtin_amdgcn_s_getreg(20 | (31 << 11)) & 7u; // HW_REG_XCC_ID
        if (tid == 0) {
            __hip_atomic_store(&roster[bid], xcc, __ATOMIC_RELAXED, __HIP_MEMORY_SCOPE_AGENT);
            asm volatile("s_waitcnt vmcnt(0)" ::: "memory");
            atomicAdd(rcount, 1u);
            while (__hip_atomic_load(rcount, __ATOMIC_RELAXED, __HIP_MEMORY_SCOPE_AGENT) < 256u)
                __builtin_amdgcn_s_sleep(2);
        }
        __syncthreads();
        sR[tid] = __hip_atomic_load(&roster[tid], __ATOMIC_RELAXED, __HIP_MEMORY_SCOPE_AGENT);
        __syncthreads();
        if (tid == 0) {
            int cnt[8] = {0,0,0,0,0,0,0,0};
            int myrank = 0, myx = 0;
            for (int b = 0; b < 256; ++b) {
                int x = (int)(sR[b] & 7u);
                int r = cnt[x]++;
                if (b == bid) { myrank = r; myx = x; }
            }
            int pre[9]; pre[0] = 0;
            for (int x = 0; x < 8; ++x) pre[x + 1] = pre[x] + cnt[x];
            int gidx = pre[myx] + myrank;
            int gr = gidx >> 4, sl = gidx & 15;
            int lo = gr << 4, hi = lo + 16, fok = 0;
            for (int x = 0; x < 8; ++x)
                if (pre[x] <= lo && hi <= pre[x + 1]) fok = 1;
            sA[0] = gr; sA[1] = sl; sA[2] = fok;
        }
        __syncthreads();
        group = sA[0]; slot = sA[1]; fastm = (sA[2] != 0);
    } else {
        group = bid / WGSPC; slot = bid % WGSPC; fastm = false;
    }

    uint* abortp = abortf + group;
    const int wic     = slot * 4 + wave;
    const int rowbase = slot * 64 + wave * 16;
    const int rowwg   = slot * 64;
    const int ck0     = group * ilv;

    // ---- one-time: stage the WG's 64 W_hh rows into LDS as bf16 pairs ----
    for (int idx = tid; idx < 64 * 512; idx += BLOCK) {
        const int r = idx >> 9, p = idx & 511;
        const float2 w = *(const float2*)&W_hh[(size_t)(rowwg + r) * H + 2 * p];
        sW[r][p] = f2bf(w.x) | (f2bf(w.y) << 16);
    }
    __syncthreads();

    const int myrow = rowbase + (lane & 15);
    const float wih_s = W_ih[myrow];
    const float cb_s  = b_ih[myrow] + b_hh[myrow];

    f32x4 wo4[4];
    #pragma unroll
    for (int q = 0; q < 4; ++q)
        wo4[q] = *(const f32x4*)&W_out[256 * q + 4 * lane];
    const float bo = b_out[0];

    int ns[4], t0c[4];
    #pragma unroll
    for (int k = 0; k < 4; ++k) {
        const int ck = ck0 + k;
        const int w_ = (k < ilv && ck) ? WARM : 0;
        ns[k]  = (k < ilv) ? chunk + w_ : 0;
        t0c[k] = ck * chunk - w_;
    }

    f32x4 hrv[4][4] = {};            // hrv[k][q] = h[256q + 4l .. +3], h_0=0
    float lv0[4] = {0,0,0,0}, lv1[4] = {0,0,0,0};
    uint  lastflag[4] = {0,0,0,0};
    float xcur[4] = {0,0,0,0};
    #pragma unroll
    for (int k = 0; k < 4; ++k)
        if (k < ilv) xcur[k] = xs[t0c[k]];

    auto demote = [&]() {
        #pragma unroll
        for (int k = 0; k < 4; ++k) {
            if (k >= ilv) continue;
            float* hbk = hdata + (size_t)(ck0 + k) * 2 * H;
            float* q0 = hbk + rowbase + (lane & 15);
            float* q1 = q0 + H;
            if (lane < 16) {
                asm volatile("global_store_dword %0, %1, off sc0 sc1"
                             :: "v"(q0), "v"(lv0[k]) : "memory");
                asm volatile("global_store_dword %0, %1, off sc0 sc1"
                             :: "v"(q1), "v"(lv1[k]) : "memory");
            }
            asm volatile("s_waitcnt vmcnt(0)" ::: "memory");
            if (lane == 0)
                asm volatile("global_store_dword %0, %1, off sc0 sc1"
                             :: "v"(flbase + (ck0 + k) * 64 + wic), "v"(lastflag[k]) : "memory");
        }
        asm volatile("s_waitcnt vmcnt(0)" ::: "memory");
        if (lane == 0)
            asm volatile("global_store_dword %0, %1, off sc0 sc1"
                         :: "v"(abortp), "v"(1u) : "memory");
        asm volatile("s_waitcnt vmcnt(0)" ::: "memory");
        fastm = false;
    };

    auto abort_set = [&]() -> bool {
        uint ab;
        asm volatile("global_load_dword %0, %1, off sc0 sc1\n\ts_waitcnt vmcnt(0)"
                     : "=v"(ab) : "v"(abortp) : "memory");
        return __any(ab != 0u);
    };

    // single-chain poll+load (fallback path + tails); writes out[16]
    auto poll_load_t = [&](int ck, int lt, float* out) {
        const uint* fa = flbase + ck * 64 + lane;
        const uint tt = (uint)lt;
        uint fails = 0;
        for (;;) {
            uint f;
            if (fastm)
                asm volatile("global_load_dword %0, %1, off sc0\n\ts_waitcnt vmcnt(0)"
                             : "=v"(f) : "v"(fa) : "memory");
            else
                asm volatile("global_load_dword %0, %1, off sc0 sc1\n\ts_waitcnt vmcnt(0)"
                             : "=v"(f) : "v"(fa) : "memory");
            if (__all(f >= tt)) break;
            ++fails;
            if (fastm) {
                if ((fails & 63u) == 0u) {
                    if (abort_set() || fails > 8192u) demote();
                }
                __builtin_amdgcn_s_sleep(1);
            } else {
                __builtin_amdgcn_s_sleep(8);
            }
        }
        const float* a = hdata + (size_t)ck * 2 * H + (size_t)(lt & 1) * H + 4 * lane;
        f32x4 A, B, C, D;
        if (fastm)
            asm volatile(
                "global_load_dwordx4 %0, %4, off sc0\n\t"
                "global_load_dwordx4 %1, %4, off offset:1024 sc0\n\t"
                "global_load_dwordx4 %2, %4, off offset:2048 sc0\n\t"
                "global_load_dwordx4 %3, %4, off offset:3072 sc0\n\t"
                "s_waitcnt vmcnt(0)"
                : "=&v"(A), "=&v"(B), "=&v"(C), "=&v"(D) : "v"(a) : "memory");
        else
            asm volatile(
                "global_load_dwordx4 %0, %4, off sc0 sc1\n\t"
                "global_load_dwordx4 %1, %4, off offset:1024 sc0 sc1\n\t"
                "global_load_dwordx4 %2, %4, off offset:2048 sc0 sc1\n\t"
                "global_load_dwordx4 %3, %4, off offset:3072 sc0 sc1\n\t"
                "s_waitcnt vmcnt(0)"
                : "=&v"(A), "=&v"(B), "=&v"(C), "=&v"(D) : "v"(a) : "memory");
        #pragma unroll
        for (int e = 0; e < 4; ++e) {
            out[e] = A[e]; out[4 + e] = B[e]; out[8 + e] = C[e]; out[12 + e] = D[e];
        }
    };

    auto reduce16 = [&](const float* z) -> float {
        float s0,s1,s2,s3,s4,s5,s6,s7;
        {
            const bool b = (lane & 1) != 0;
            s0 = (b ? z[ 1] : z[ 0]) + __shfl_xor(b ? z[ 0] : z[ 1], 1);
            s1 = (b ? z[ 3] : z[ 2]) + __shfl_xor(b ? z[ 2] : z[ 3], 1);
            s2 = (b ? z[ 5] : z[ 4]) + __shfl_xor(b ? z[ 4] : z[ 5], 1);
            s3 = (b ? z[ 7] : z[ 6]) + __shfl_xor(b ? z[ 6] : z[ 7], 1);
            s4 = (b ? z[ 9] : z[ 8]) + __shfl_xor(b ? z[ 8] : z[ 9], 1);
            s5 = (b ? z[11] : z[10]) + __shfl_xor(b ? z[10] : z[11], 1);
            s6 = (b ? z[13] : z[12]) + __shfl_xor(b ? z[12] : z[13], 1);
            s7 = (b ? z[15] : z[14]) + __shfl_xor(b ? z[14] : z[15], 1);
        }
        float t0_,t1_,t2_,t3_;
        {
            const bool b = (lane & 2) != 0;
            t0_ = (b ? s1 : s0) + __shfl_xor(b ? s0 : s1, 2);
            t1_ = (b ? s3 : s2) + __shfl_xor(b ? s2 : s3, 2);
            t2_ = (b ? s5 : s4) + __shfl_xor(b ? s4 : s5, 2);
            t3_ = (b ? s7 : s6) + __shfl_xor(b ? s6 : s7, 2);
        }
        float u0_,u1_;
        {
            const bool b = (lane & 4) != 0;
            u0_ = (b ? t1_ : t0_) + __shfl_xor(b ? t0_ : t1_, 4);
            u1_ = (b ? t3_ : t2_) + __shfl_xor(b ? t2_ : t3_, 4);
        }
        float zr;
        {
            const bool b = (lane & 8) != 0;
            zr = (b ? u1_ : u0_) + __shfl_xor(b ? u0_ : u1_, 8);
        }
        zr += __shfl_xor(zr, 16);
        zr += __shfl_xor(zr, 32);
        return zr;
    };

    const int nstep_max = chunk + ((ilv > 1 || group) ? WARM : 0);

    #pragma unroll 1
    for (int it = 0; it < nstep_max; ++it) {
        if (fastm && (it & 31) == 1) {
            if (abort_set()) demote();
        }

        // ---- phase 1: compute chains SEQUENTIALLY (z scoped per chain) ----
        float hv[4] = {0, 0, 0, 0};
        #pragma unroll
        for (int k = 0; k < 4; ++k) {
            if (k >= ilv || it >= ns[k]) continue;
            float z[16];
            #pragma unroll
            for (int r = 0; r < 16; ++r) {
                const uint2* wrow = (const uint2*)&sW[wave * 16 + r][2 * lane];
                float a = 0.0f;
                #pragma unroll
                for (int q = 0; q < 4; ++q) {
                    const uint2 u = wrow[q * 64];
                    a = fmaf(__uint_as_float(u.x << 16),         hrv[k][q][0], a);
                    a = fmaf(__uint_as_float(u.x & 0xffff0000u), hrv[k][q][1], a);
                    a = fmaf(__uint_as_float(u.y << 16),         hrv[k][q][2], a);
                    a = fmaf(__uint_as_float(u.y & 0xffff0000u), hrv[k][q][3], a);
                }
                z[r] = a;
            }
            hv[k] = tanhf(fmaf(xcur[k], wih_s, cb_s + reduce16(z)));
        }

        // ---- phase 2: publish all (h stores -> ONE vmcnt -> flag stores) --
        const int par = (it + 1) & 1;
        #pragma unroll
        for (int k = 0; k < 4; ++k) {
            if (k >= ilv || it >= ns[k]) continue;
            float* dst = hdata + (size_t)((ck0 + k) * 2 + par) * H + rowbase + (lane & 15);
            if (lane < 16) {
                if (fastm)
                    asm volatile("global_store_dword %0, %1, off"
                                 :: "v"(dst), "v"(hv[k]) : "memory");
                else
                    asm volatile("global_store_dword %0, %1, off sc0 sc1"
                                 :: "v"(dst), "v"(hv[k]) : "memory");
            }
        }
        asm volatile("s_waitcnt vmcnt(0)" ::: "memory");
        #pragma unroll
        for (int k = 0; k < 4; ++k) {
            if (k >= ilv || it >= ns[k]) continue;
            const uint nf = (uint)(it + 1);
            if (lane == 0) {
                if (fastm)
                    asm volatile("global_store_dword %0, %1, off"
                                 :: "v"(flbase + (ck0 + k) * 64 + wic), "v"(nf) : "memory");
                else
                    asm volatile("global_store_dword %0, %1, off sc0 sc1"
                                 :: "v"(flbase + (ck0 + k) * 64 + wic), "v"(nf) : "memory");
            }
            if (par == 0) lv0[k] = hv[k]; else lv1[k] = hv[k];
            lastflag[k] = nf;
        }

        // ---- y duty (uses h_it = hrv, park in LDS) ----
        #pragma unroll
        for (int k = 0; k < 4; ++k) {
            if (k >= ilv || it >= ns[k]) continue;
            const int warm_k = (ck0 + k) ? WARM : 0;
            if (wic == (it & 63) && it >= warm_k + 1) {
                float acc = 0.0f;
                #pragma unroll
                for (int q = 0; q < 4; ++q) {
                    acc = fmaf(wo4[q][0], hrv[k][q][0], acc);
                    acc = fmaf(wo4[q][1], hrv[k][q][1], acc);
                    acc = fmaf(wo4[q][2], hrv[k][q][2], acc);
                    acc = fmaf(wo4[q][3], hrv[k][q][3], acc);
                }
                #pragma unroll
                for (int off = 32; off > 0; off >>= 1)
                    acc += __shfl_xor(acc, off);
                if (lane == 0) {
                    if (coop) sY[wave][k][it >> 6] = acc + bo;
                    else      y[t0c[k] + it - 1] = acc + bo;
                }
            }
            if (it + 1 < ns[k]) xcur[k] = xs[t0c[k] + it + 1];
        }

        // ---- phases 3+4: combined poll (1 RT) + combined load (1 RT) ----
        if (ilv == 4) {
            uint tg0 = (it + 1 < ns[0]) ? (uint)(it + 1) : 0u;
            uint tg1 = (it + 1 < ns[1]) ? (uint)(it + 1) : 0u;
            uint tg2 = (it + 1 < ns[2]) ? (uint)(it + 1) : 0u;
            uint tg3 = (it + 1 < ns[3]) ? (uint)(it + 1) : 0u;
            if (tg0 | tg1 | tg2 | tg3) {
                const uint* fa = flbase + ck0 * 64 + lane;
                uint fails = 0;
                for (;;) {
                    uint f0, f1, f2, f3;
                    if (fastm)
                        asm volatile(
                            "global_load_dword %0, %4, off sc0\n\t"
                            "global_load_dword %1, %4, off offset:256 sc0\n\t"
                            "global_load_dword %2, %4, off offset:512 sc0\n\t"
                            "global_load_dword %3, %4, off offset:768 sc0\n\t"
                            "s_waitcnt vmcnt(0)"
                            : "=&v"(f0), "=&v"(f1), "=&v"(f2), "=&v"(f3)
                            : "v"(fa) : "memory");
                    else
                        asm volatile(
                            "global_load_dword %0, %4, off sc0 sc1\n\t"
                            "global_load_dword %1, %4, off offset:256 sc0 sc1\n\t"
                            "global_load_dword %2, %4, off offset:512 sc0 sc1\n\t"
                            "global_load_dword %3, %4, off offset:768 sc0 sc1\n\t"
                            "s_waitcnt vmcnt(0)"
                            : "=&v"(f0), "=&v"(f1), "=&v"(f2), "=&v"(f3)
                            : "v"(fa) : "memory");
                    bool ok = (f0 >= tg0) & (f1 >= tg1) & (f2 >= tg2) & (f3 >= tg3);
                    if (__all(ok)) break;
                    ++fails;
                    if (fastm) {
                        if ((fails & 63u) == 0u) {
                            if (abort_set() || fails > 8192u) demote();
                        }
                        __builtin_amdgcn_s_sleep(1);
                    } else {
                        __builtin_amdgcn_s_sleep(8);
                    }
                }
                const float* a0p = hdata + (size_t)(ck0 * 2 + par) * H + 4 * lane;
                const float* a1p = a0p + 2 * H;
                const float* a2p = a0p + 4 * H;
                const float* a3p = a0p + 6 * H;
                if (fastm)
                    asm volatile(
                        "global_load_dwordx4 %0, %16, off sc0\n\t"
                        "global_load_dwordx4 %1, %16, off offset:1024 sc0\n\t"
                        "global_load_dwordx4 %2, %16, off offset:2048 sc0\n\t"
                        "global_load_dwordx4 %3, %16, off offset:3072 sc0\n\t"
                        "global_load_dwordx4 %4, %17, off sc0\n\t"
                        "global_load_dwordx4 %5, %17, off offset:1024 sc0\n\t"
                        "global_load_dwordx4 %6, %17, off offset:2048 sc0\n\t"
                        "global_load_dwordx4 %7, %17, off offset:3072 sc0\n\t"
                        "global_load_dwordx4 %8, %18, off sc0\n\t"
                        "global_load_dwordx4 %9, %18, off offset:1024 sc0\n\t"
                        "global_load_dwordx4 %10, %18, off offset:2048 sc0\n\t"
                        "global_load_dwordx4 %11, %18, off offset:3072 sc0\n\t"
                        "global_load_dwordx4 %12, %19, off sc0\n\t"
                        "global_load_dwordx4 %13, %19, off offset:1024 sc0\n\t"
                        "global_load_dwordx4 %14, %19, off offset:2048 sc0\n\t"
                        "global_load_dwordx4 %15, %19, off offset:3072 sc0\n\t"
                        "s_waitcnt vmcnt(0)"
                        : "=&v"(hrv[0][0]), "=&v"(hrv[0][1]), "=&v"(hrv[0][2]), "=&v"(hrv[0][3]),
                          "=&v"(hrv[1][0]), "=&v"(hrv[1][1]), "=&v"(hrv[1][2]), "=&v"(hrv[1][3]),
                          "=&v"(hrv[2][0]), "=&v"(hrv[2][1]), "=&v"(hrv[2][2]), "=&v"(hrv[2][3]),
                          "=&v"(hrv[3][0]), "=&v"(hrv[3][1]), "=&v"(hrv[3][2]), "=&v"(hrv[3][3])
                        : "v"(a0p), "v"(a1p), "v"(a2p), "v"(a3p) : "memory");
                else
                    asm volatile(
                        "global_load_dwordx4 %0, %16, off sc0 sc1\n\t"
                        "global_load_dwordx4 %1, %16, off offset:1024 sc0 sc1\n\t"
                        "global_load_dwordx4 %2, %16, off offset:2048 sc0 sc1\n\t"
                        "global_load_dwordx4 %3, %16, off offset:3072 sc0 sc1\n\t"
                        "global_load_dwordx4 %4, %17, off sc0 sc1\n\t"
                        "global_load_dwordx4 %5, %17, off offset:1024 sc0 sc1\n\t"
                        "global_load_dwordx4 %6, %17, off offset:2048 sc0 sc1\n\t"
                        "global_load_dwordx4 %7, %17, off offset:3072 sc0 sc1\n\t"
                        "global_load_dwordx4 %8, %18, off sc0 sc1\n\t"
                        "global_load_dwordx4 %9, %18, off offset:1024 sc0 sc1\n\t"
                        "global_load_dwordx4 %10, %18, off offset:2048 sc0 sc1\n\t"
                        "global_load_dwordx4 %11, %18, off offset:3072 sc0 sc1\n\t"
                        "global_load_dwordx4 %12, %19, off sc0 sc1\n\t"
                        "global_load_dwordx4 %13, %19, off offset:1024 sc0 sc1\n\t"
                        "global_load_dwordx4 %14, %19, off offset:2048 sc0 sc1\n\t"
                        "global_load_dwordx4 %15, %19, off offset:3072 sc0 sc1\n\t"
                        "s_waitcnt vmcnt(0)"
                        : "=&v"(hrv[0][0]), "=&v"(hrv[0][1]), "=&v"(hrv[0][2]), "=&v"(hrv[0][3]),
                          "=&v"(hrv[1][0]), "=&v"(hrv[1][1]), "=&v"(hrv[1][2]), "=&v"(hrv[1][3]),
                          "=&v"(hrv[2][0]), "=&v"(hrv[2][1]), "=&v"(hrv[2][2]), "=&v"(hrv[2][3]),
                          "=&v"(hrv[3][0]), "=&v"(hrv[3][1]), "=&v"(hrv[3][2]), "=&v"(hrv[3][3])
                        : "v"(a0p), "v"(a1p), "v"(a2p), "v"(a3p) : "memory");
            }
        } else {
            if (it + 1 < ns[0]) {
                float out[16];
                poll_load_t(ck0, it + 1, out);
                #pragma unroll
                for (int q = 0; q < 4; ++q)
                    #pragma unroll
                    for (int e = 0; e < 4; ++e)
                        hrv[0][q][e] = out[4 * q + e];
            }
        }
    }

    // ---- flush parked y (coop): it = 64*kk + wic -> y[t0+it-1] ----
    if (coop) {
        #pragma unroll
        for (int k = 0; k < 4; ++k) {
            if (k >= ilv) continue;
            const int warm_k = (ck0 + k) ? WARM : 0;
            #pragma unroll 1
            for (int kk = 0; kk < 8; ++kk) {
                const int it = (kk << 6) + wic;
                if (it >= warm_k + 1 && it < ns[k] && lane == 0)
                    y[t0c[k] + it - 1] = sY[wave][k][kk];
            }
        }
    }

    // tail: y[t0+nstep-1] from h_nstep (slot 0, wave 0 per chain)
    if (slot == 0 && wave == 0) {
        #pragma unroll
        for (int k = 0; k < 4; ++k) {
            if (k >= ilv) continue;
            float out[16];
            poll_load_t(ck0 + k, ns[k], out);
            float acc = 0.0f;
            #pragma unroll
            for (int q = 0; q < 4; ++q) {
                acc = fmaf(wo4[q][0], out[4 * q + 0], acc);
                acc = fmaf(wo4[q][1], out[4 * q + 1], acc);
                acc = fmaf(wo4[q][2], out[4 * q + 2], acc);
                acc = fmaf(wo4[q][3], out[4 * q + 3], acc);
            }
            #pragma unroll
            for (int off = 32; off > 0; off >>= 1)
                acc += __shfl_xor(acc, off);
            if (lane == 0) y[t0c[k] + ns[k] - 1] = acc + bo;
        }
    }
}

extern "C" void kernel_launch(void* const* d_in, const int* in_sizes, int n_in,
                              void* d_out, int out_size, void* d_ws, size_t ws_size,
                              hipStream_t stream) {
    const float* xs    = (const float*)d_in[0];
    const float* W_ih  = (const float*)d_in[1];
    const float* b_ih  = (const float*)d_in[2];
    const float* W_hh  = (const float*)d_in[3];
    const float* b_hh  = (const float*)d_in[4];
    const float* W_out = (const float*)d_in[5];
    const float* b_out = (const float*)d_in[6];
    float* y = (float*)d_out;

    const size_t ctrl_bytes = 24576;
    const size_t need = HDATA_BYTES + ctrl_bytes;
    int use_coop = (ws_size >= need) ? 1 : 0;

    float* hdata = (float*)d_ws;
    uint*  ctrl  = (uint*)((char*)d_ws +
                           (use_coop ? HDATA_BYTES
                                     : (size_t)4 * 2 * H * sizeof(float)));

    (void)hipMemsetAsync(d_ws, 0,
                         use_coop ? need
                                  : (size_t)4 * 2 * H * sizeof(float) + ctrl_bytes,
                         stream);

    if (use_coop) {
        int coop = 1, ilv = 4, chunk = TSTEPS / 64;          // 64 chains x 320
        void* args[] = { (void*)&xs, (void*)&W_ih, (void*)&b_ih, (void*)&W_hh,
                         (void*)&b_hh, (void*)&W_out, (void*)&b_out, (void*)&y,
                         (void*)&hdata, (void*)&ctrl,
                         (void*)&coop, (void*)&ilv, (void*)&chunk };
        hipError_t e = hipLaunchCooperativeKernel((const void*)rnn_r21,
                                                  dim3(256), dim3(BLOCK),
                                                  args, 0, stream);
        if (e != hipSuccess) use_coop = 0;
    }
    if (!use_coop) {
        rnn_r21<<<4 * WGSPC, BLOCK, 0, stream>>>(
            xs, W_ih, b_ih, W_hh, b_hh, W_out, b_out, y,
            hdata, ctrl, 0, 1, TSTEPS / 4);
    }
}

// Round 21
// 4995.906 us; speedup vs baseline: 10.2798x; 1.1981x over previous
//
#include <hip/hip_runtime.h>
#include <math.h>

// DummyRNN: h = tanh(x_t*w_ih + b_ih + W_hh@h + b_hh); y_t = W_out@h + b_out
//
// R22 = R21 (4-way chain interleave, batched publish/poll/load, XCD-local
// flag-split sync, W_hh bf16 in LDS) with phase 1 computing chains in
// FUSED PAIRS (0,1) then (2,3). R21 post-mortem: per-segment cost 3.4us of
// which ~2.3us is exposed dependency stalls (1 wave/SIMD, no TLP): serial
// shfl tree, serial tanh, ds_read->FMA waits. Pair fusion gives 2
// independent chains of everything -> ILP hides ~half the stalls. Register
// cost +16 VGPR only (za+zb live; R19's bomb was all four z's + hrv).

#define H      1024
#define TSTEPS 20480
#define BLOCK  256
#define WARM   64
#define WGSPC  16

typedef unsigned int uint;
typedef float f32x4 __attribute__((ext_vector_type(4)));

#define HDATA_BYTES ((size_t)64 * 2 * H * sizeof(float))   // 512 KB (coop)

__device__ __forceinline__ uint f2bf(float f) {            // fp32 -> bf16 RNE
    uint u = __float_as_uint(f);
    return (u + 0x7fffu + ((u >> 16) & 1u)) >> 16;
}

__global__ __launch_bounds__(BLOCK, 1)
void rnn_r22(const float* __restrict__ xs, const float* __restrict__ W_ih,
             const float* __restrict__ b_ih, const float* __restrict__ W_hh,
             const float* __restrict__ b_hh, const float* __restrict__ W_out,
             const float* __restrict__ b_out, float* __restrict__ y,
             float* __restrict__ hdata, uint* __restrict__ ctrl,
             int coop, int ilv, int chunk)
{
    const int tid  = threadIdx.x;
    const int bid  = blockIdx.x;
    const int wave = tid >> 6;
    const int lane = tid & 63;

    __shared__ uint  sW[64][512];    // 128 KB: 64 rows of W_hh as bf16 pairs
    __shared__ uint  sR[256];
    __shared__ int   sA[3];
    __shared__ float sY[4][4][8];    // [wave][k][it>>6] parked y (coop)

    uint* rcount = ctrl;             // [0]
    uint* abortf = ctrl + 16;        // [16..31] per-GROUP abort flags
    uint* roster = ctrl + 64;        // [64..319]
    uint* flbase = ctrl + 1024;      // 64 chains x 64 per-wave flags

    int group, slot; bool fastm;
    if (coop) {
        uint xcc = __builtin_amdgcn_s_getreg(20 | (31 << 11)) & 7u; // HW_REG_XCC_ID
        if (tid == 0) {
            __hip_atomic_store(&roster[bid], xcc, __ATOMIC_RELAXED, __HIP_MEMORY_SCOPE_AGENT);
            asm volatile("s_waitcnt vmcnt(0)" ::: "memory");
            atomicAdd(rcount, 1u);
            while (__hip_atomic_load(rcount, __ATOMIC_RELAXED, __HIP_MEMORY_SCOPE_AGENT) < 256u)
                __builtin_amdgcn_s_sleep(2);
        }
        __syncthreads();
        sR[tid] = __hip_atomic_load(&roster[tid], __ATOMIC_RELAXED, __HIP_MEMORY_SCOPE_AGENT);
        __syncthreads();
        if (tid == 0) {
            int cnt[8] = {0,0,0,0,0,0,0,0};
            int myrank = 0, myx = 0;
            for (int b = 0; b < 256; ++b) {
                int x = (int)(sR[b] & 7u);
                int r = cnt[x]++;
                if (b == bid) { myrank = r; myx = x; }
            }
            int pre[9]; pre[0] = 0;
            for (int x = 0; x < 8; ++x) pre[x + 1] = pre[x] + cnt[x];
            int gidx = pre[myx] + myrank;
            int gr = gidx >> 4, sl = gidx & 15;
            int lo = gr << 4, hi = lo + 16, fok = 0;
            for (int x = 0; x < 8; ++x)
                if (pre[x] <= lo && hi <= pre[x + 1]) fok = 1;
            sA[0] = gr; sA[1] = sl; sA[2] = fok;
        }
        __syncthreads();
        group = sA[0]; slot = sA[1]; fastm = (sA[2] != 0);
    } else {
        group = bid / WGSPC; slot = bid % WGSPC; fastm = false;
    }

    uint* abortp = abortf + group;
    const int wic     = slot * 4 + wave;
    const int rowbase = slot * 64 + wave * 16;
    const int rowwg   = slot * 64;
    const int ck0     = group * ilv;

    // ---- one-time: stage the WG's 64 W_hh rows into LDS as bf16 pairs ----
    for (int idx = tid; idx < 64 * 512; idx += BLOCK) {
        const int r = idx >> 9, p = idx & 511;
        const float2 w = *(const float2*)&W_hh[(size_t)(rowwg + r) * H + 2 * p];
        sW[r][p] = f2bf(w.x) | (f2bf(w.y) << 16);
    }
    __syncthreads();

    const int myrow = rowbase + (lane & 15);
    const float wih_s = W_ih[myrow];
    const float cb_s  = b_ih[myrow] + b_hh[myrow];

    f32x4 wo4[4];
    #pragma unroll
    for (int q = 0; q < 4; ++q)
        wo4[q] = *(const f32x4*)&W_out[256 * q + 4 * lane];
    const float bo = b_out[0];

    int ns[4], t0c[4];
    #pragma unroll
    for (int k = 0; k < 4; ++k) {
        const int ck = ck0 + k;
        const int w_ = (k < ilv && ck) ? WARM : 0;
        ns[k]  = (k < ilv) ? chunk + w_ : 0;
        t0c[k] = ck * chunk - w_;
    }

    f32x4 hrv[4][4] = {};            // hrv[k][q] = h[256q + 4l .. +3], h_0=0
    float lv0[4] = {0,0,0,0}, lv1[4] = {0,0,0,0};
    uint  lastflag[4] = {0,0,0,0};
    float xcur[4] = {0,0,0,0};
    #pragma unroll
    for (int k = 0; k < 4; ++k)
        if (k < ilv) xcur[k] = xs[t0c[k]];

    auto demote = [&]() {
        #pragma unroll
        for (int k = 0; k < 4; ++k) {
            if (k >= ilv) continue;
            float* hbk = hdata + (size_t)(ck0 + k) * 2 * H;
            float* q0 = hbk + rowbase + (lane & 15);
            float* q1 = q0 + H;
            if (lane < 16) {
                asm volatile("global_store_dword %0, %1, off sc0 sc1"
                             :: "v"(q0), "v"(lv0[k]) : "memory");
                asm volatile("global_store_dword %0, %1, off sc0 sc1"
                             :: "v"(q1), "v"(lv1[k]) : "memory");
            }
            asm volatile("s_waitcnt vmcnt(0)" ::: "memory");
            if (lane == 0)
                asm volatile("global_store_dword %0, %1, off sc0 sc1"
                             :: "v"(flbase + (ck0 + k) * 64 + wic), "v"(lastflag[k]) : "memory");
        }
        asm volatile("s_waitcnt vmcnt(0)" ::: "memory");
        if (lane == 0)
            asm volatile("global_store_dword %0, %1, off sc0 sc1"
                         :: "v"(abortp), "v"(1u) : "memory");
        asm volatile("s_waitcnt vmcnt(0)" ::: "memory");
        fastm = false;
    };

    auto abort_set = [&]() -> bool {
        uint ab;
        asm volatile("global_load_dword %0, %1, off sc0 sc1\n\ts_waitcnt vmcnt(0)"
                     : "=v"(ab) : "v"(abortp) : "memory");
        return __any(ab != 0u);
    };

    // single-chain poll+load (fallback path + tails); writes out[16]
    auto poll_load_t = [&](int ck, int lt, float* out) {
        const uint* fa = flbase + ck * 64 + lane;
        const uint tt = (uint)lt;
        uint fails = 0;
        for (;;) {
            uint f;
            if (fastm)
                asm volatile("global_load_dword %0, %1, off sc0\n\ts_waitcnt vmcnt(0)"
                             : "=v"(f) : "v"(fa) : "memory");
            else
                asm volatile("global_load_dword %0, %1, off sc0 sc1\n\ts_waitcnt vmcnt(0)"
                             : "=v"(f) : "v"(fa) : "memory");
            if (__all(f >= tt)) break;
            ++fails;
            if (fastm) {
                if ((fails & 63u) == 0u) {
                    if (abort_set() || fails > 8192u) demote();
                }
                __builtin_amdgcn_s_sleep(1);
            } else {
                __builtin_amdgcn_s_sleep(8);
            }
        }
        const float* a = hdata + (size_t)ck * 2 * H + (size_t)(lt & 1) * H + 4 * lane;
        f32x4 A, B, C, D;
        if (fastm)
            asm volatile(
                "global_load_dwordx4 %0, %4, off sc0\n\t"
                "global_load_dwordx4 %1, %4, off offset:1024 sc0\n\t"
                "global_load_dwordx4 %2, %4, off offset:2048 sc0\n\t"
                "global_load_dwordx4 %3, %4, off offset:3072 sc0\n\t"
                "s_waitcnt vmcnt(0)"
                : "=&v"(A), "=&v"(B), "=&v"(C), "=&v"(D) : "v"(a) : "memory");
        else
            asm volatile(
                "global_load_dwordx4 %0, %4, off sc0 sc1\n\t"
                "global_load_dwordx4 %1, %4, off offset:1024 sc0 sc1\n\t"
                "global_load_dwordx4 %2, %4, off offset:2048 sc0 sc1\n\t"
                "global_load_dwordx4 %3, %4, off offset:3072 sc0 sc1\n\t"
                "s_waitcnt vmcnt(0)"
                : "=&v"(A), "=&v"(B), "=&v"(C), "=&v"(D) : "v"(a) : "memory");
        #pragma unroll
        for (int e = 0; e < 4; ++e) {
            out[e] = A[e]; out[4 + e] = B[e]; out[8 + e] = C[e]; out[12 + e] = D[e];
        }
    };

    // single reduce (tail/fallback)
    auto reduce16 = [&](const float* z) -> float {
        float s0,s1,s2,s3,s4,s5,s6,s7;
        {
            const bool b = (lane & 1) != 0;
            s0 = (b ? z[ 1] : z[ 0]) + __shfl_xor(b ? z[ 0] : z[ 1], 1);
            s1 = (b ? z[ 3] : z[ 2]) + __shfl_xor(b ? z[ 2] : z[ 3], 1);
            s2 = (b ? z[ 5] : z[ 4]) + __shfl_xor(b ? z[ 4] : z[ 5], 1);
            s3 = (b ? z[ 7] : z[ 6]) + __shfl_xor(b ? z[ 6] : z[ 7], 1);
            s4 = (b ? z[ 9] : z[ 8]) + __shfl_xor(b ? z[ 8] : z[ 9], 1);
            s5 = (b ? z[11] : z[10]) + __shfl_xor(b ? z[10] : z[11], 1);
            s6 = (b ? z[13] : z[12]) + __shfl_xor(b ? z[12] : z[13], 1);
            s7 = (b ? z[15] : z[14]) + __shfl_xor(b ? z[14] : z[15], 1);
        }
        float t0_,t1_,t2_,t3_;
        {
            const bool b = (lane & 2) != 0;
            t0_ = (b ? s1 : s0) + __shfl_xor(b ? s0 : s1, 2);
            t1_ = (b ? s3 : s2) + __shfl_xor(b ? s2 : s3, 2);
            t2_ = (b ? s5 : s4) + __shfl_xor(b ? s4 : s5, 2);
            t3_ = (b ? s7 : s6) + __shfl_xor(b ? s6 : s7, 2);
        }
        float u0_,u1_;
        {
            const bool b = (lane & 4) != 0;
            u0_ = (b ? t1_ : t0_) + __shfl_xor(b ? t0_ : t1_, 4);
            u1_ = (b ? t3_ : t2_) + __shfl_xor(b ? t2_ : t3_, 4);
        }
        float zr;
        {
            const bool b = (lane & 8) != 0;
            zr = (b ? u1_ : u0_) + __shfl_xor(b ? u0_ : u1_, 8);
        }
        zr += __shfl_xor(zr, 16);
        zr += __shfl_xor(zr, 32);
        return zr;
    };

    // paired reduce: two independent trees interleaved stage-by-stage so the
    // serial bpermute latency of one tree hides under the other's
    auto reduce16x2 = [&](const float* za, const float* zb, float& ra, float& rb) {
        const bool b1 = (lane & 1) != 0;
        float sa0 = (b1 ? za[ 1] : za[ 0]) + __shfl_xor(b1 ? za[ 0] : za[ 1], 1);
        float sb0 = (b1 ? zb[ 1] : zb[ 0]) + __shfl_xor(b1 ? zb[ 0] : zb[ 1], 1);
        float sa1 = (b1 ? za[ 3] : za[ 2]) + __shfl_xor(b1 ? za[ 2] : za[ 3], 1);
        float sb1 = (b1 ? zb[ 3] : zb[ 2]) + __shfl_xor(b1 ? zb[ 2] : zb[ 3], 1);
        float sa2 = (b1 ? za[ 5] : za[ 4]) + __shfl_xor(b1 ? za[ 4] : za[ 5], 1);
        float sb2 = (b1 ? zb[ 5] : zb[ 4]) + __shfl_xor(b1 ? zb[ 4] : zb[ 5], 1);
        float sa3 = (b1 ? za[ 7] : za[ 6]) + __shfl_xor(b1 ? za[ 6] : za[ 7], 1);
        float sb3 = (b1 ? zb[ 7] : zb[ 6]) + __shfl_xor(b1 ? zb[ 6] : zb[ 7], 1);
        float sa4 = (b1 ? za[ 9] : za[ 8]) + __shfl_xor(b1 ? za[ 8] : za[ 9], 1);
        float sb4 = (b1 ? zb[ 9] : zb[ 8]) + __shfl_xor(b1 ? zb[ 8] : zb[ 9], 1);
        float sa5 = (b1 ? za[11] : za[10]) + __shfl_xor(b1 ? za[10] : za[11], 1);
        float sb5 = (b1 ? zb[11] : zb[10]) + __shfl_xor(b1 ? zb[10] : zb[11], 1);
        float sa6 = (b1 ? za[13] : za[12]) + __shfl_xor(b1 ? za[12] : za[13], 1);
        float sb6 = (b1 ? zb[13] : zb[12]) + __shfl_xor(b1 ? zb[12] : zb[13], 1);
        float sa7 = (b1 ? za[15] : za[14]) + __shfl_xor(b1 ? za[14] : za[15], 1);
        float sb7 = (b1 ? zb[15] : zb[14]) + __shfl_xor(b1 ? zb[14] : zb[15], 1);
        const bool b2 = (lane & 2) != 0;
        float ta0 = (b2 ? sa1 : sa0) + __shfl_xor(b2 ? sa0 : sa1, 2);
        float tb0 = (b2 ? sb1 : sb0) + __shfl_xor(b2 ? sb0 : sb1, 2);
        float ta1 = (b2 ? sa3 : sa2) + __shfl_xor(b2 ? sa2 : sa3, 2);
        float tb1 = (b2 ? sb3 : sb2) + __shfl_xor(b2 ? sb2 : sb3, 2);
        float ta2 = (b2 ? sa5 : sa4) + __shfl_xor(b2 ? sa4 : sa5, 2);
        float tb2 = (b2 ? sb5 : sb4) + __shfl_xor(b2 ? sb4 : sb5, 2);
        float ta3 = (b2 ? sa7 : sa6) + __shfl_xor(b2 ? sa6 : sa7, 2);
        float tb3 = (b2 ? sb7 : sb6) + __shfl_xor(b2 ? sb6 : sb7, 2);
        const bool b4 = (lane & 4) != 0;
        float ua0 = (b4 ? ta1 : ta0) + __shfl_xor(b4 ? ta0 : ta1, 4);
        float ub0 = (b4 ? tb1 : tb0) + __shfl_xor(b4 ? tb0 : tb1, 4);
        float ua1 = (b4 ? ta3 : ta2) + __shfl_xor(b4 ? ta2 : ta3, 4);
        float ub1 = (b4 ? tb3 : tb2) + __shfl_xor(b4 ? tb2 : tb3, 4);
        const bool b8 = (lane & 8) != 0;
        float va = (b8 ? ua1 : ua0) + __shfl_xor(b8 ? ua0 : ua1, 8);
        float vb = (b8 ? ub1 : ub0) + __shfl_xor(b8 ? ub0 : ub1, 8);
        va += __shfl_xor(va, 16);
        vb += __shfl_xor(vb, 16);
        va += __shfl_xor(va, 32);
        vb += __shfl_xor(vb, 32);
        ra = va; rb = vb;
    };

    const int nstep_max = chunk + ((ilv > 1 || group) ? WARM : 0);

    #pragma unroll 1
    for (int it = 0; it < nstep_max; ++it) {
        if (fastm && (it & 31) == 1) {
            if (abort_set()) demote();
        }

        // ---- phase 1: compute chains in FUSED PAIRS (ILP hides stalls) ----
        float hv[4] = {0, 0, 0, 0};
        #pragma unroll
        for (int kp = 0; kp < 2; ++kp) {
            const int ka = 2 * kp, kb = 2 * kp + 1;
            const bool doa = (ka < ilv) && (it < ns[ka]);
            const bool dob = (kb < ilv) && (it < ns[kb]);
            if (!doa && !dob) continue;
            float za[16], zb[16];
            #pragma unroll
            for (int r = 0; r < 16; ++r) {
                const uint2* wrow = (const uint2*)&sW[wave * 16 + r][2 * lane];
                float a = 0.0f, b = 0.0f;
                #pragma unroll
                for (int q = 0; q < 4; ++q) {
                    const uint2 u = wrow[q * 64];
                    const float w0 = __uint_as_float(u.x << 16);
                    const float w1 = __uint_as_float(u.x & 0xffff0000u);
                    const float w2 = __uint_as_float(u.y << 16);
                    const float w3 = __uint_as_float(u.y & 0xffff0000u);
                    a = fmaf(w0, hrv[ka][q][0], a);
                    b = fmaf(w0, hrv[kb][q][0], b);
                    a = fmaf(w1, hrv[ka][q][1], a);
                    b = fmaf(w1, hrv[kb][q][1], b);
                    a = fmaf(w2, hrv[ka][q][2], a);
                    b = fmaf(w2, hrv[kb][q][2], b);
                    a = fmaf(w3, hrv[ka][q][3], a);
                    b = fmaf(w3, hrv[kb][q][3], b);
                }
                za[r] = a; zb[r] = b;
            }
            float zra, zrb;
            reduce16x2(za, zb, zra, zrb);
            // two independent tanh chains (compiler interleaves)
            const float va = fmaf(xcur[ka], wih_s, cb_s + zra);
            const float vb = fmaf(xcur[kb], wih_s, cb_s + zrb);
            const float ha = tanhf(va);
            const float hb = tanhf(vb);
            if (doa) hv[ka] = ha;
            if (dob) hv[kb] = hb;
        }

        // ---- phase 2: publish all (h stores -> ONE vmcnt -> flag stores) --
        const int par = (it + 1) & 1;
        #pragma unroll
        for (int k = 0; k < 4; ++k) {
            if (k >= ilv || it >= ns[k]) continue;
            float* dst = hdata + (size_t)((ck0 + k) * 2 + par) * H + rowbase + (lane & 15);
            if (lane < 16) {
                if (fastm)
                    asm volatile("global_store_dword %0, %1, off"
                                 :: "v"(dst), "v"(hv[k]) : "memory");
                else
                    asm volatile("global_store_dword %0, %1, off sc0 sc1"
                                 :: "v"(dst), "v"(hv[k]) : "memory");
            }
        }
        asm volatile("s_waitcnt vmcnt(0)" ::: "memory");
        #pragma unroll
        for (int k = 0; k < 4; ++k) {
            if (k >= ilv || it >= ns[k]) continue;
            const uint nf = (uint)(it + 1);
            if (lane == 0) {
                if (fastm)
                    asm volatile("global_store_dword %0, %1, off"
                                 :: "v"(flbase + (ck0 + k) * 64 + wic), "v"(nf) : "memory");
                else
                    asm volatile("global_store_dword %0, %1, off sc0 sc1"
                                 :: "v"(flbase + (ck0 + k) * 64 + wic), "v"(nf) : "memory");
            }
            if (par == 0) lv0[k] = hv[k]; else lv1[k] = hv[k];
            lastflag[k] = nf;
        }

        // ---- y duty (uses h_it = hrv, park in LDS) ----
        #pragma unroll
        for (int k = 0; k < 4; ++k) {
            if (k >= ilv || it >= ns[k]) continue;
            const int warm_k = (ck0 + k) ? WARM : 0;
            if (wic == (it & 63) && it >= warm_k + 1) {
                float acc = 0.0f;
                #pragma unroll
                for (int q = 0; q < 4; ++q) {
                    acc = fmaf(wo4[q][0], hrv[k][q][0], acc);
                    acc = fmaf(wo4[q][1], hrv[k][q][1], acc);
                    acc = fmaf(wo4[q][2], hrv[k][q][2], acc);
                    acc = fmaf(wo4[q][3], hrv[k][q][3], acc);
                }
                #pragma unroll
                for (int off = 32; off > 0; off >>= 1)
                    acc += __shfl_xor(acc, off);
                if (lane == 0) {
                    if (coop) sY[wave][k][it >> 6] = acc + bo;
                    else      y[t0c[k] + it - 1] = acc + bo;
                }
            }
            if (it + 1 < ns[k]) xcur[k] = xs[t0c[k] + it + 1];
        }

        // ---- phases 3+4: combined poll (1 RT) + combined load (1 RT) ----
        if (ilv == 4) {
            uint tg0 = (it + 1 < ns[0]) ? (uint)(it + 1) : 0u;
            uint tg1 = (it + 1 < ns[1]) ? (uint)(it + 1) : 0u;
            uint tg2 = (it + 1 < ns[2]) ? (uint)(it + 1) : 0u;
            uint tg3 = (it + 1 < ns[3]) ? (uint)(it + 1) : 0u;
            if (tg0 | tg1 | tg2 | tg3) {
                const uint* fa = flbase + ck0 * 64 + lane;
                uint fails = 0;
                for (;;) {
                    uint f0, f1, f2, f3;
                    if (fastm)
                        asm volatile(
                            "global_load_dword %0, %4, off sc0\n\t"
                            "global_load_dword %1, %4, off offset:256 sc0\n\t"
                            "global_load_dword %2, %4, off offset:512 sc0\n\t"
                            "global_load_dword %3, %4, off offset:768 sc0\n\t"
                            "s_waitcnt vmcnt(0)"
                            : "=&v"(f0), "=&v"(f1), "=&v"(f2), "=&v"(f3)
                            : "v"(fa) : "memory");
                    else
                        asm volatile(
                            "global_load_dword %0, %4, off sc0 sc1\n\t"
                            "global_load_dword %1, %4, off offset:256 sc0 sc1\n\t"
                            "global_load_dword %2, %4, off offset:512 sc0 sc1\n\t"
                            "global_load_dword %3, %4, off offset:768 sc0 sc1\n\t"
                            "s_waitcnt vmcnt(0)"
                            : "=&v"(f0), "=&v"(f1), "=&v"(f2), "=&v"(f3)
                            : "v"(fa) : "memory");
                    bool ok = (f0 >= tg0) & (f1 >= tg1) & (f2 >= tg2) & (f3 >= tg3);
                    if (__all(ok)) break;
                    ++fails;
                    if (fastm) {
                        if ((fails & 63u) == 0u) {
                            if (abort_set() || fails > 8192u) demote();
                        }
                        __builtin_amdgcn_s_sleep(1);
                    } else {
                        __builtin_amdgcn_s_sleep(8);
                    }
                }
                const float* a0p = hdata + (size_t)(ck0 * 2 + par) * H + 4 * lane;
                const float* a1p = a0p + 2 * H;
                const float* a2p = a0p + 4 * H;
                const float* a3p = a0p + 6 * H;
                if (fastm)
                    asm volatile(
                        "global_load_dwordx4 %0, %16, off sc0\n\t"
                        "global_load_dwordx4 %1, %16, off offset:1024 sc0\n\t"
                        "global_load_dwordx4 %2, %16, off offset:2048 sc0\n\t"
                        "global_load_dwordx4 %3, %16, off offset:3072 sc0\n\t"
                        "global_load_dwordx4 %4, %17, off sc0\n\t"
                        "global_load_dwordx4 %5, %17, off offset:1024 sc0\n\t"
                        "global_load_dwordx4 %6, %17, off offset:2048 sc0\n\t"
                        "global_load_dwordx4 %7, %17, off offset:3072 sc0\n\t"
                        "global_load_dwordx4 %8, %18, off sc0\n\t"
                        "global_load_dwordx4 %9, %18, off offset:1024 sc0\n\t"
                        "global_load_dwordx4 %10, %18, off offset:2048 sc0\n\t"
                        "global_load_dwordx4 %11, %18, off offset:3072 sc0\n\t"
                        "global_load_dwordx4 %12, %19, off sc0\n\t"
                        "global_load_dwordx4 %13, %19, off offset:1024 sc0\n\t"
                        "global_load_dwordx4 %14, %19, off offset:2048 sc0\n\t"
                        "global_load_dwordx4 %15, %19, off offset:3072 sc0\n\t"
                        "s_waitcnt vmcnt(0)"
                        : "=&v"(hrv[0][0]), "=&v"(hrv[0][1]), "=&v"(hrv[0][2]), "=&v"(hrv[0][3]),
                          "=&v"(hrv[1][0]), "=&v"(hrv[1][1]), "=&v"(hrv[1][2]), "=&v"(hrv[1][3]),
                          "=&v"(hrv[2][0]), "=&v"(hrv[2][1]), "=&v"(hrv[2][2]), "=&v"(hrv[2][3]),
                          "=&v"(hrv[3][0]), "=&v"(hrv[3][1]), "=&v"(hrv[3][2]), "=&v"(hrv[3][3])
                        : "v"(a0p), "v"(a1p), "v"(a2p), "v"(a3p) : "memory");
                else
                    asm volatile(
                        "global_load_dwordx4 %0, %16, off sc0 sc1\n\t"
                        "global_load_dwordx4 %1, %16, off offset:1024 sc0 sc1\n\t"
                        "global_load_dwordx4 %2, %16, off offset:2048 sc0 sc1\n\t"
                        "global_load_dwordx4 %3, %16, off offset:3072 sc0 sc1\n\t"
                        "global_load_dwordx4 %4, %17, off sc0 sc1\n\t"
                        "global_load_dwordx4 %5, %17, off offset:1024 sc0 sc1\n\t"
                        "global_load_dwordx4 %6, %17, off offset:2048 sc0 sc1\n\t"
                        "global_load_dwordx4 %7, %17, off offset:3072 sc0 sc1\n\t"
                        "global_load_dwordx4 %8, %18, off sc0 sc1\n\t"
                        "global_load_dwordx4 %9, %18, off offset:1024 sc0 sc1\n\t"
                        "global_load_dwordx4 %10, %18, off offset:2048 sc0 sc1\n\t"
                        "global_load_dwordx4 %11, %18, off offset:3072 sc0 sc1\n\t"
                        "global_load_dwordx4 %12, %19, off sc0 sc1\n\t"
                        "global_load_dwordx4 %13, %19, off offset:1024 sc0 sc1\n\t"
                        "global_load_dwordx4 %14, %19, off offset:2048 sc0 sc1\n\t"
                        "global_load_dwordx4 %15, %19, off offset:3072 sc0 sc1\n\t"
                        "s_waitcnt vmcnt(0)"
                        : "=&v"(hrv[0][0]), "=&v"(hrv[0][1]), "=&v"(hrv[0][2]), "=&v"(hrv[0][3]),
                          "=&v"(hrv[1][0]), "=&v"(hrv[1][1]), "=&v"(hrv[1][2]), "=&v"(hrv[1][3]),
                          "=&v"(hrv[2][0]), "=&v"(hrv[2][1]), "=&v"(hrv[2][2]), "=&v"(hrv[2][3]),
                          "=&v"(hrv[3][0]), "=&v"(hrv[3][1]), "=&v"(hrv[3][2]), "=&v"(hrv[3][3])
                        : "v"(a0p), "v"(a1p), "v"(a2p), "v"(a3p) : "memory");
            }
        } else {
            if (it + 1 < ns[0]) {
                float out[16];
                poll_load_t(ck0, it + 1, out);
                #pragma unroll
                for (int q = 0; q < 4; ++q)
                    #pragma unroll
                    for (int e = 0; e < 4; ++e)
                        hrv[0][q][e] = out[4 * q + e];
            }
        }
    }

    // ---- flush parked y (coop): it = 64*kk + wic -> y[t0+it-1] ----
    if (coop) {
        #pragma unroll
        for (int k = 0; k < 4; ++k) {
            if (k >= ilv) continue;
            const int warm_k = (ck0 + k) ? WARM : 0;
            #pragma unroll 1
            for (int kk = 0; kk < 8; ++kk) {
                const int it = (kk << 6) + wic;
                if (it >= warm_k + 1 && it < ns[k] && lane == 0)
                    y[t0c[k] + it - 1] = sY[wave][k][kk];
            }
        }
    }

    // tail: y[t0+nstep-1] from h_nstep (slot 0, wave 0 per chain)
    if (slot == 0 && wave == 0) {
        #pragma unroll
        for (int k = 0; k < 4; ++k) {
            if (k >= ilv) continue;
            float out[16];
            poll_load_t(ck0 + k, ns[k], out);
            float acc = 0.0f;
            #pragma unroll
            for (int q = 0; q < 4; ++q) {
                acc = fmaf(wo4[q][0], out[4 * q + 0], acc);
                acc = fmaf(wo4[q][1], out[4 * q + 1], acc);
                acc = fmaf(wo4[q][2], out[4 * q + 2], acc);
                acc = fmaf(wo4[q][3], out[4 * q + 3], acc);
            }
            #pragma unroll
            for (int off = 32; off > 0; off >>= 1)
                acc += __shfl_xor(acc, off);
            if (lane == 0) y[t0c[k] + ns[k] - 1] = acc + bo;
        }
    }
}

extern "C" void kernel_launch(void* const* d_in, const int* in_sizes, int n_in,
                              void* d_out, int out_size, void* d_ws, size_t ws_size,
                              hipStream_t stream) {
    const float* xs    = (const float*)d_in[0];
    const float* W_ih  = (const float*)d_in[1];
    const float* b_ih  = (const float*)d_in[2];
    const float* W_hh  = (const float*)d_in[3];
    const float* b_hh  = (const float*)d_in[4];
    const float* W_out = (const float*)d_in[5];
    const float* b_out = (const float*)d_in[6];
    float* y = (float*)d_out;

    const size_t ctrl_bytes = 24576;
    const size_t need = HDATA_BYTES + ctrl_bytes;
    int use_coop = (ws_size >= need) ? 1 : 0;

    float* hdata = (float*)d_ws;
    uint*  ctrl  = (uint*)((char*)d_ws +
                           (use_coop ? HDATA_BYTES
                                     : (size_t)4 * 2 * H * sizeof(float)));

    (void)hipMemsetAsync(d_ws, 0,
                         use_coop ? need
                                  : (size_t)4 * 2 * H * sizeof(float) + ctrl_bytes,
                         stream);

    if (use_coop) {
        int coop = 1, ilv = 4, chunk = TSTEPS / 64;          // 64 chains x 320
        void* args[] = { (void*)&xs, (void*)&W_ih, (void*)&b_ih, (void*)&W_hh,
                         (void*)&b_hh, (void*)&W_out, (void*)&b_out, (void*)&y,
                         (void*)&hdata, (void*)&ctrl,
                         (void*)&coop, (void*)&ilv, (void*)&chunk };
        hipError_t e = hipLaunchCooperativeKernel((const void*)rnn_r22,
                                                  dim3(256), dim3(BLOCK),
                                                  args, 0, stream);
        if (e != hipSuccess) use_coop = 0;
    }
    if (!use_coop) {
        rnn_r22<<<4 * WGSPC, BLOCK, 0, stream>>>(
            xs, W_ih, b_ih, W_hh, b_hh, W_out, b_out, y,
            hdata, ctrl, 0, 1, TSTEPS / 4);
    }
}